// Round 4
// baseline (2446.918 us; speedup 1.0000x reference)
//
#include <hip/hip_runtime.h>
#include <hip/hip_bf16.h>
#include <string.h>

// Problem constants
#define B_ 64
#define T_ 256
#define F_ 64
#define U_ 512
#define G4_ 2048     // 4*U
#define KTOT 576     // F + U   (input proj folded into recurrent matmul as extra K)
#define KSTEPS 18    // KTOT/32

typedef __attribute__((ext_vector_type(8))) short short8;
typedef __attribute__((ext_vector_type(4))) float v4f;
typedef unsigned short u16;

__device__ __forceinline__ float bf2f(u16 b) {
    unsigned int x = ((unsigned int)b) << 16;
    float f; memcpy(&f, &x, 4); return f;
}
__device__ __forceinline__ u16 f2bf(float f) {
    __hip_bfloat16 h = __float2bfloat16(f);
    u16 b; memcpy(&b, &h, 2); return b;
}
__device__ __forceinline__ float sigmoidf_(float x) { return 1.f / (1.f + __expf(-x)); }

// Dtype-flexible element load: fg=1 -> fp32, fg=0 -> bf16.
__device__ __forceinline__ float ldany(const void* p, size_t i, int fg) {
    return fg ? ((const float*)p)[i] : bf2f(((const u16*)p)[i]);
}

// Workspace layout (bytes; offsets 64-aligned).  Total 5,057,664 B (known-good).
#define WS_FLAG   0             // int flag @0, int cnt @32
#define WS_XB     64            // bf16 [T][B][F]          2,097,152
#define WS_WP     2097216       // bf16 packed weights     2,359,296
#define WS_H2     4456512       // bf16 [2][B][U]            131,072
#define WS_C      4587584       // fp32 [B][U]               131,072
#define WS_DOT    4718656       // fp32 [B][T]                65,536
#define WS_BIASF  4784192       // fp32 [4U]                   8,192
#define WS_ATTWF  4792384       // fp32 [T][T]               262,144
#define WS_ATTBF  5054528       // fp32 [T]                    1,024
#define WS_OUTWF  5055552       // fp32 [U]                    2,048
#define WS_OUTBF  5057600       // fp32 [1]                       64
#define WS_NEED   5057664

// ---------------------------------------------------------------------------
// Kernel 0: dtype detection (flag: 1 = fp32 inputs, 0 = bf16) + zero the
// grid-barrier counter.  See round-3 notes: exponent-band vote on `kernel`.
// ---------------------------------------------------------------------------
__global__ __launch_bounds__(256) void detect(const unsigned int* __restrict__ w,
                                              int* __restrict__ flag,
                                              int* __restrict__ cnt) {
    __shared__ int votes;
    if (threadIdx.x == 0) votes = 0;
    if (threadIdx.x == 1) *cnt = 0;
    __syncthreads();
    unsigned int v = w[threadIdx.x];
    int e = (v >> 7) & 0xFF;
    if (e >= 100 && e <= 135) atomicAdd(&votes, 1);
    __syncthreads();
    if (threadIdx.x == 0) *flag = (votes < 200) ? 1 : 0;
}

// ---------------------------------------------------------------------------
// Kernel 1: canonicalize inputs.  x -> xb bf16 [T][B][F]; small arrays ->
// fp32; dot -> 0.  Flat task space, grid 4428*256 >= 1,133,313.
// ---------------------------------------------------------------------------
__global__ __launch_bounds__(256) void convert(const void* __restrict__ x,
                                               const void* __restrict__ bias,
                                               const void* __restrict__ attW,
                                               const void* __restrict__ attb,
                                               const void* __restrict__ outW,
                                               const void* __restrict__ outb,
                                               const int* __restrict__ flag,
                                               u16* __restrict__ xb,
                                               float* __restrict__ biasf,
                                               float* __restrict__ attWf,
                                               float* __restrict__ attbf,
                                               float* __restrict__ outWf,
                                               float* __restrict__ outbf,
                                               float* __restrict__ dot) {
    int fg = *flag;
    size_t i = (size_t)blockIdx.x * 256 + threadIdx.x;
    if (i < 1048576) {
        float v = ldany(x, i, fg);
        int b = (int)(i >> 14), t = (int)((i >> 6) & 255), f = (int)(i & 63);
        xb[((size_t)t * B_ + b) * F_ + f] = f2bf(v);
        return;
    }
    i -= 1048576;
    if (i < 2048)  { biasf[i] = ldany(bias, i, fg); return; }
    i -= 2048;
    if (i < 65536) { attWf[i] = ldany(attW, i, fg); return; }
    i -= 65536;
    if (i < 256)   { attbf[i] = ldany(attb, i, fg); return; }
    i -= 256;
    if (i < 512)   { outWf[i] = ldany(outW, i, fg); return; }
    i -= 512;
    if (i < 1)     { outbf[i] = ldany(outb, i, fg); return; }
    i -= 1;
    if (i < 16384) { dot[i] = 0.f; return; }
}

// ---------------------------------------------------------------------------
// Kernel 2: pack [kernel(64,2048); rec_kernel(512,2048)] into MFMA-B-fragment
// layout, column permutation c' = 4*u + gate (orig col = gate*512 + u) so a
// 32-col slice holds all 4 gates of 8 hidden units.  Lane l of fragment
// (nt, ks) supplies B[k = ks*32 + (l>>4)*8 + j][col = nt*16 + (l&15)].
// ---------------------------------------------------------------------------
__global__ __launch_bounds__(256) void pack_w(const void* __restrict__ kin,
                                              const void* __restrict__ krec,
                                              const int* __restrict__ flag,
                                              u16* __restrict__ Wp) {
    int fg = *flag;
    int gid = blockIdx.x * 256 + threadIdx.x;   // grid = 576*256 == 128*18*64
    int lane = gid & 63;
    int frag = gid >> 6;
    int nt = frag / KSTEPS;
    int ks = frag - nt * KSTEPS;
    int kbase = ks * 32 + (lane >> 4) * 8;
    int cp = nt * 16 + (lane & 15);
    int u = cp >> 2, gate = cp & 3;
    int C = gate * U_ + u;
    short8 v;
    for (int j = 0; j < 8; j++) {
        int k = kbase + j;
        float w = (k < F_) ? ldany(kin, (size_t)k * G4_ + C, fg)
                           : ldany(krec, (size_t)(k - F_) * G4_ + C, fg);
        v[j] = (short)f2bf(w);
    }
    *reinterpret_cast<short8*>(Wp + (size_t)gid * 8) = v;
}

// ---------------------------------------------------------------------------
// Kernel 3: PERSISTENT LSTM.  grid = 64 blocks (block b owns hidden units
// [8b,8b+8)), 256 threads = 4 waves; all blocks co-resident on 256 CUs.
// Weights staged into LDS ONCE; 256 timesteps in-kernel, separated by a
// device-scope grid barrier (monotone counter).  dot partials accumulate in
// LDS and flush via atomicAdd every 32 steps (off the barrier critical path).
// ---------------------------------------------------------------------------
__global__ __launch_bounds__(256) void lstm_persist(const u16* __restrict__ xb,
                                                    const float* __restrict__ biasf,
                                                    const float* __restrict__ outWf,
                                                    const u16* __restrict__ Wp,
                                                    u16* __restrict__ h2,
                                                    float* __restrict__ c,
                                                    float* __restrict__ dot,
                                                    int* __restrict__ cnt) {
    __shared__ __align__(16) u16 Bs[KSTEPS * 2 * 64 * 8];   // 36 KB weights
    __shared__ __align__(16) float gbuf[64][32];            // 8 KB gate preacts
    __shared__ float dp[32][64];                            // 8 KB dot partials

    int tid = threadIdx.x;
    int b = blockIdx.x;

    // Stage the block's B-slice (n-tiles 2b, 2b+1) into LDS: 2304 16B chunks.
    for (int i = 0; i < 9; i++) {
        int chunk = i * 256 + tid;            // 0..2303
        int ks = chunk >> 7;
        int rem = chunk & 127;
        int tile = rem >> 6;
        int lane = rem & 63;
        int nt = 2 * b + tile;
        short8 v = *reinterpret_cast<const short8*>(Wp + ((size_t)(nt * KSTEPS + ks) * 64 + lane) * 8);
        *reinterpret_cast<short8*>(&Bs[((ks * 2 + tile) * 64 + lane) * 8]) = v;
    }

    // Per-thread constants (ui invariant across both elementwise iterations).
    int ui = tid & 7;
    int ug = b * 8 + ui;
    float bia = biasf[0 * U_ + ug];
    float bif = biasf[1 * U_ + ug];
    float big = biasf[2 * U_ + ug];
    float bio = biasf[3 * U_ + ug];
    float wout = outWf[ug];

    int w = tid >> 6, lane = tid & 63;
    int arow = w * 16 + (lane & 15);          // A-operand row (batch index)
    int koff = (lane >> 4) * 8;
    u16* hb0 = h2;                            // ping-pong buffers
    u16* hb1 = h2 + B_ * U_;
    __syncthreads();

    for (int t = 0; t < T_; t++) {
        u16* hcur = (t & 1) ? hb1 : hb0;
        const u16* hrow = ((t & 1) ? hb0 : hb1) + (size_t)arow * U_;
        const u16* xrow = xb + ((size_t)t * B_ + arow) * F_;

        v4f acc0 = {0.f, 0.f, 0.f, 0.f}, acc1 = {0.f, 0.f, 0.f, 0.f};
        int kmax = (t == 0) ? 2 : KSTEPS;     // t==0: h_prev == 0
        for (int ks = 0; ks < kmax; ks++) {
            int k = ks * 32 + koff;
            const u16* ap = (k < F_) ? (xrow + k) : (hrow + (k - F_));
            short8 a = *reinterpret_cast<const short8*>(ap);
            short8 b0 = *reinterpret_cast<const short8*>(&Bs[((ks * 2 + 0) * 64 + lane) * 8]);
            short8 b1 = *reinterpret_cast<const short8*>(&Bs[((ks * 2 + 1) * 64 + lane) * 8]);
            acc0 = __builtin_amdgcn_mfma_f32_16x16x32_bf16(a, b0, acc0, 0, 0, 0);
            acc1 = __builtin_amdgcn_mfma_f32_16x16x32_bf16(a, b1, acc1, 0, 0, 0);
        }

        // D layout: lane holds D[row=(l>>4)*4+r][col=l&15]
        {
            int col0 = lane & 15;
            int rbase = w * 16 + (lane >> 4) * 4;
            for (int r = 0; r < 4; r++) {
                gbuf[rbase + r][col0]      = acc0[r];
                gbuf[rbase + r][16 + col0] = acc1[r];
            }
        }
        __syncthreads();

        // Elementwise: 512 items (64 rows x 8 local u), 2 per thread.
        for (int it = 0; it < 2; it++) {
            int item = it * 256 + tid;
            int r  = item >> 3;
            int cl = ui * 4;
            float gi = gbuf[r][cl + 0] + bia;
            float gf = gbuf[r][cl + 1] + bif;
            float gg = gbuf[r][cl + 2] + big;
            float go = gbuf[r][cl + 3] + bio;
            float ig = sigmoidf_(gi), fg = sigmoidf_(gf), og = sigmoidf_(go);
            float gc = tanhf(gg);
            float cold = (t == 0) ? 0.f : c[(size_t)r * U_ + ug];
            float cn = fg * cold + ig * gc;
            c[(size_t)r * U_ + ug] = cn;
            float h = og * tanhf(cn);
            hcur[(size_t)r * U_ + ug] = f2bf(h);

            // dot partial: 8 lanes (same r) reduce h*outW over their units.
            float hw = h * wout;
            hw += __shfl_xor(hw, 1, 64);
            hw += __shfl_xor(hw, 2, 64);
            hw += __shfl_xor(hw, 4, 64);
            if (ui == 0) dp[t & 31][r] = hw;
        }
        __syncthreads();                      // dp writes + gbuf reads done

        // Flush dot partials every 32 steps (2048 entries, 8 atomics/thread).
        if ((t & 31) == 31) {
            int t0 = t - 31;
            for (int idx = tid; idx < 2048; idx += 256) {
                int tt = idx >> 6, rr = idx & 63;
                atomicAdd(&dot[(size_t)rr * T_ + (t0 + tt)], dp[tt][rr]);
            }
        }

        // Grid barrier (skip after the last step).
        if (t < T_ - 1) {
            __syncthreads();
            if (tid == 0) {
                __threadfence();              // release: h stores visible at IC
                __hip_atomic_fetch_add(cnt, 1, __ATOMIC_RELEASE, __HIP_MEMORY_SCOPE_AGENT);
                int target = 64 * (t + 1);
                int spins = 0;
                while (__hip_atomic_load(cnt, __ATOMIC_RELAXED, __HIP_MEMORY_SCOPE_AGENT) < target) {
                    if (++spins > (1 << 22)) break;   // bailout: never hang
                }
                __threadfence();              // acquire: see fresh h
            }
            __syncthreads();
        }
    }
}

// ---------------------------------------------------------------------------
// Kernel 4: finale.  attention collapses to scalars:
//   coef_t = (t==0) ? 1 : sum_{j<t} att_W[t,j];  shift_t = (t==0) ? 0 : att_b[t]
//   out[b,t] = sigmoid(coef_t * dot[b,t] + shift_t * sum(out_W) + out_b)
// grid = 256 (one block per t).  Output dtype follows the input dtype flag.
// ---------------------------------------------------------------------------
__global__ __launch_bounds__(256) void finale(const float* __restrict__ attWf,
                                              const float* __restrict__ attbf,
                                              const float* __restrict__ outWf,
                                              const float* __restrict__ outbf,
                                              const float* __restrict__ dot,
                                              const int* __restrict__ flag,
                                              void* __restrict__ out) {
    __shared__ float red[256];
    int t = blockIdx.x, tid = threadIdx.x;
    int fg = *flag;

    float v = (tid < t) ? attWf[(size_t)t * T_ + tid] : 0.f;
    red[tid] = v; __syncthreads();
    for (int s = 128; s > 0; s >>= 1) { if (tid < s) red[tid] += red[tid + s]; __syncthreads(); }
    float coef = (t == 0) ? 1.f : red[0];
    __syncthreads();
    red[tid] = outWf[tid] + outWf[tid + 256]; __syncthreads();
    for (int s = 128; s > 0; s >>= 1) { if (tid < s) red[tid] += red[tid + s]; __syncthreads(); }
    float sumW = red[0];

    float base = ((t == 0) ? 0.f : attbf[t]) * sumW + outbf[0];

    if (tid < B_) {
        float s = sigmoidf_(coef * dot[(size_t)tid * T_ + t] + base);
        size_t idx = (size_t)tid * T_ + t;
        if (fg) ((float*)out)[idx] = s;
        else    ((u16*)out)[idx] = f2bf(s);
    }
}

// ---------------------------------------------------------------------------
extern "C" void kernel_launch(void* const* d_in, const int* in_sizes, int n_in,
                              void* d_out, int out_size, void* d_ws, size_t ws_size,
                              hipStream_t stream) {
    const void* x    = d_in[0];   // inputs (64,256,64)
    const void* kin  = d_in[1];   // kernel (64,2048)
    const void* krec = d_in[2];   // rec_kernel (512,2048)
    const void* bias = d_in[3];   // (2048,)
    const void* attW = d_in[4];   // (256,256)
    const void* attb = d_in[5];   // (256,)
    const void* outW = d_in[6];   // (512,)
    const void* outb = d_in[7];   // ()

    if (ws_size < (size_t)WS_NEED) return;   // diagnostic: output stays memset-0

    char* ws = (char*)d_ws;
    int*   flag  = (int*)(ws + WS_FLAG);
    int*   cnt   = (int*)(ws + WS_FLAG + 32);
    u16*   xb    = (u16*)(ws + WS_XB);
    u16*   Wp    = (u16*)(ws + WS_WP);
    u16*   h2    = (u16*)(ws + WS_H2);       // [2][64][512] bf16 ping-pong
    float* c     = (float*)(ws + WS_C);
    float* dot   = (float*)(ws + WS_DOT);
    float* biasf = (float*)(ws + WS_BIASF);
    float* attWf = (float*)(ws + WS_ATTWF);
    float* attbf = (float*)(ws + WS_ATTBF);
    float* outWf = (float*)(ws + WS_OUTWF);
    float* outbf = (float*)(ws + WS_OUTBF);

    detect<<<1, 256, 0, stream>>>((const unsigned int*)kin, flag, cnt);
    convert<<<4428, 256, 0, stream>>>(x, bias, attW, attb, outW, outb, flag,
                                      xb, biasf, attWf, attbf, outWf, outbf, dot);
    pack_w<<<576, 256, 0, stream>>>(kin, krec, flag, Wp);
    lstm_persist<<<64, 256, 0, stream>>>(xb, biasf, outWf, Wp, h2, c, dot, cnt);
    finale<<<256, 256, 0, stream>>>(attWf, attbf, outWf, outbf, dot, flag, d_out);
}

// Round 5
// 2045.054 us; speedup vs baseline: 1.1965x; 1.1965x over previous
//
#include <hip/hip_runtime.h>
#include <hip/hip_bf16.h>
#include <string.h>

// Problem constants
#define B_ 64
#define T_ 256
#define F_ 64
#define U_ 512
#define G4_ 2048     // 4*U
#define KTOT 576     // F + U   (input proj folded into recurrent matmul as extra K)
#define KSTEPS 18    // KTOT/32

typedef __attribute__((ext_vector_type(8))) short short8;
typedef __attribute__((ext_vector_type(4))) float v4f;
typedef unsigned short u16;
typedef unsigned long long ull;

__device__ __forceinline__ float bf2f(u16 b) {
    unsigned int x = ((unsigned int)b) << 16;
    float f; memcpy(&f, &x, 4); return f;
}
__device__ __forceinline__ u16 f2bf(float f) {
    __hip_bfloat16 h = __float2bfloat16(f);
    u16 b; memcpy(&b, &h, 2); return b;
}
__device__ __forceinline__ float sigmoidf_(float x) { return 1.f / (1.f + __expf(-x)); }

// Dtype-flexible element load: fg=1 -> fp32, fg=0 -> bf16.
__device__ __forceinline__ float ldany(const void* p, size_t i, int fg) {
    return fg ? ((const float*)p)[i] : bf2f(((const u16*)p)[i]);
}

// Workspace layout (bytes; offsets 64-aligned).
#define WS_FLAG   0             // int dtype-flag @0
#define WS_XB     64            // bf16 [T][B][F]          2,097,152
#define WS_WP     2097216       // bf16 packed weights     2,359,296
#define WS_H2     4456512       // bf16 [2][B][U]            131,072
#define WS_C      4587584       // (unused now)              131,072
#define WS_DOT    4718656       // fp32 [B][T]                65,536
#define WS_BIASF  4784192       // fp32 [4U]                   8,192
#define WS_ATTWF  4792384       // fp32 [T][T]               262,144
#define WS_ATTBF  5054528       // fp32 [T]                    1,024
#define WS_OUTWF  5055552       // fp32 [U]                    2,048
#define WS_OUTBF  5057600       // fp32 [1]                       64
#define WS_FLAGS  5057664       // int [64] barrier flags        256
#define WS_NEED   5057920

// ---------------------------------------------------------------------------
// Kernel 0: dtype detection (flag: 1 = fp32 inputs, 0 = bf16) + zero the
// 64 per-block barrier flags (end-of-kernel writeback makes the zeros visible
// to lstm_persist's sc1 polls).
// ---------------------------------------------------------------------------
__global__ __launch_bounds__(256) void detect(const unsigned int* __restrict__ w,
                                              int* __restrict__ flag,
                                              int* __restrict__ flags) {
    __shared__ int votes;
    if (threadIdx.x == 0) votes = 0;
    if (threadIdx.x < 64) flags[threadIdx.x] = 0;
    __syncthreads();
    unsigned int v = w[threadIdx.x];
    int e = (v >> 7) & 0xFF;
    if (e >= 100 && e <= 135) atomicAdd(&votes, 1);
    __syncthreads();
    if (threadIdx.x == 0) *flag = (votes < 200) ? 1 : 0;
}

// ---------------------------------------------------------------------------
// Kernel 1: canonicalize inputs.  x -> xb bf16 [T][B][F]; small arrays ->
// fp32; dot -> 0.  Flat task space, grid 4428*256 >= 1,133,313.
// ---------------------------------------------------------------------------
__global__ __launch_bounds__(256) void convert(const void* __restrict__ x,
                                               const void* __restrict__ bias,
                                               const void* __restrict__ attW,
                                               const void* __restrict__ attb,
                                               const void* __restrict__ outW,
                                               const void* __restrict__ outb,
                                               const int* __restrict__ flag,
                                               u16* __restrict__ xb,
                                               float* __restrict__ biasf,
                                               float* __restrict__ attWf,
                                               float* __restrict__ attbf,
                                               float* __restrict__ outWf,
                                               float* __restrict__ outbf,
                                               float* __restrict__ dot) {
    int fg = *flag;
    size_t i = (size_t)blockIdx.x * 256 + threadIdx.x;
    if (i < 1048576) {
        float v = ldany(x, i, fg);
        int b = (int)(i >> 14), t = (int)((i >> 6) & 255), f = (int)(i & 63);
        xb[((size_t)t * B_ + b) * F_ + f] = f2bf(v);
        return;
    }
    i -= 1048576;
    if (i < 2048)  { biasf[i] = ldany(bias, i, fg); return; }
    i -= 2048;
    if (i < 65536) { attWf[i] = ldany(attW, i, fg); return; }
    i -= 65536;
    if (i < 256)   { attbf[i] = ldany(attb, i, fg); return; }
    i -= 256;
    if (i < 512)   { outWf[i] = ldany(outW, i, fg); return; }
    i -= 512;
    if (i < 1)     { outbf[i] = ldany(outb, i, fg); return; }
    i -= 1;
    if (i < 16384) { dot[i] = 0.f; return; }
}

// ---------------------------------------------------------------------------
// Kernel 2: pack [kernel(64,2048); rec_kernel(512,2048)] into MFMA-B-fragment
// layout, column permutation c' = 4*u + gate (orig col = gate*512 + u) so a
// 32-col slice holds all 4 gates of 8 hidden units.  Lane l of fragment
// (nt, ks) supplies B[k = ks*32 + (l>>4)*8 + j][col = nt*16 + (l&15)].
// ---------------------------------------------------------------------------
__global__ __launch_bounds__(256) void pack_w(const void* __restrict__ kin,
                                              const void* __restrict__ krec,
                                              const int* __restrict__ flag,
                                              u16* __restrict__ Wp) {
    int fg = *flag;
    int gid = blockIdx.x * 256 + threadIdx.x;   // grid = 576*256 == 128*18*64
    int lane = gid & 63;
    int frag = gid >> 6;
    int nt = frag / KSTEPS;
    int ks = frag - nt * KSTEPS;
    int kbase = ks * 32 + (lane >> 4) * 8;
    int cp = nt * 16 + (lane & 15);
    int u = cp >> 2, gate = cp & 3;
    int C = gate * U_ + u;
    short8 v;
    for (int j = 0; j < 8; j++) {
        int k = kbase + j;
        float w = (k < F_) ? ldany(kin, (size_t)k * G4_ + C, fg)
                           : ldany(krec, (size_t)(k - F_) * G4_ + C, fg);
        v[j] = (short)f2bf(w);
    }
    *reinterpret_cast<short8*>(Wp + (size_t)gid * 8) = v;
}

// ---------------------------------------------------------------------------
// Kernel 3: PERSISTENT LSTM, fence-free.  grid = 64 blocks (block b owns
// hidden units [8b,8b+8)), 256 threads = 4 waves, guaranteed co-resident.
// Cross-block data (h, barrier flags) moves via agent-scope RELAXED atomics
// (sc1 -> IC-coherent, bypasses per-XCD L2) -- NO threadfence, so the L2
// stays warm (xb, Wp) across all 256 steps.  c lives in 2 registers/thread.
// Barrier: block publishes flags[b]=t+1; wave 0's 64 lanes each poll one flag.
// Ordering: compiler emits s_waitcnt vmcnt(0) before s_barrier, and sc1-store
// retirement == visible at IC, so flag-publish after __syncthreads is safe.
// ---------------------------------------------------------------------------
__global__ __launch_bounds__(256, 1) void lstm_persist(const u16* __restrict__ xb,
                                                       const float* __restrict__ biasf,
                                                       const float* __restrict__ outWf,
                                                       const u16* __restrict__ Wp,
                                                       u16* __restrict__ h2,
                                                       float* __restrict__ dot,
                                                       int* __restrict__ flags) {
    __shared__ __align__(16) u16 Bs[KSTEPS * 2 * 64 * 8];   // 36 KB weights
    __shared__ __align__(16) float gbuf[64][36];            // 9 KB gate preacts (padded)
    __shared__ float dp[32][64];                            // 8 KB dot partials

    int tid = threadIdx.x;
    int b = blockIdx.x;

    // Stage the block's B-slice (n-tiles 2b, 2b+1) into LDS: 2304 16B chunks.
    for (int i = 0; i < 9; i++) {
        int chunk = i * 256 + tid;            // 0..2303
        int ks = chunk >> 7;
        int rem = chunk & 127;
        int tile = rem >> 6;
        int lane2 = rem & 63;
        int nt = 2 * b + tile;
        short8 v = *reinterpret_cast<const short8*>(Wp + ((size_t)(nt * KSTEPS + ks) * 64 + lane2) * 8);
        *reinterpret_cast<short8*>(&Bs[((ks * 2 + tile) * 64 + lane2) * 8]) = v;
    }

    // Elementwise mapping: thread <-> (row r = tid>>2, unit pair p = tid&3);
    // owns global units ug0 = b*8+2p, ug0+1.  c in registers for all steps.
    int r  = tid >> 2;
    int p  = tid & 3;
    int ug0 = b * 8 + 2 * p;
    float bia0 = biasf[0 * U_ + ug0], bia1 = biasf[0 * U_ + ug0 + 1];
    float bif0 = biasf[1 * U_ + ug0], bif1 = biasf[1 * U_ + ug0 + 1];
    float big0 = biasf[2 * U_ + ug0], big1 = biasf[2 * U_ + ug0 + 1];
    float bio0 = biasf[3 * U_ + ug0], bio1 = biasf[3 * U_ + ug0 + 1];
    float wout0 = outWf[ug0], wout1 = outWf[ug0 + 1];
    float c0 = 0.f, c1 = 0.f;

    int w = tid >> 6, lane = tid & 63;
    int arow = w * 16 + (lane & 15);          // A-operand row (batch index)
    int koff = (lane >> 4) * 8;
    u16* hb0 = h2;                            // ping-pong buffers
    u16* hb1 = h2 + B_ * U_;
    __syncthreads();

    for (int t = 0; t < T_; t++) {
        u16* hcur = (t & 1) ? hb1 : hb0;
        const u16* hprev = (t & 1) ? hb0 : hb1;
        const u16* xrow = xb + ((size_t)t * B_ + arow) * F_;

        v4f acc0 = {0.f, 0.f, 0.f, 0.f}, acc1 = {0.f, 0.f, 0.f, 0.f};
        short8 a0 = *reinterpret_cast<const short8*>(xrow + koff);        // ks=0
        short8 a1 = *reinterpret_cast<const short8*>(xrow + 32 + koff);   // ks=1

        if (t > 0) {
            // Issue all 32 h loads (agent-scope sc1 -> fresh from IC) first
            // so their latency overlaps the LDS B reads + MFMAs.
            union { short8 s; ull q[2]; } af[16];
            const u16* hrow = hprev + (size_t)arow * U_;
            #pragma unroll
            for (int ks = 2; ks < KSTEPS; ks++) {
                const ull* hp = (const ull*)(hrow + (ks * 32 + koff - F_));
                af[ks - 2].q[0] = __hip_atomic_load(hp,     __ATOMIC_RELAXED, __HIP_MEMORY_SCOPE_AGENT);
                af[ks - 2].q[1] = __hip_atomic_load(hp + 1, __ATOMIC_RELAXED, __HIP_MEMORY_SCOPE_AGENT);
            }
            acc0 = __builtin_amdgcn_mfma_f32_16x16x32_bf16(a0, *reinterpret_cast<const short8*>(&Bs[((0 * 2 + 0) * 64 + lane) * 8]), acc0, 0, 0, 0);
            acc1 = __builtin_amdgcn_mfma_f32_16x16x32_bf16(a0, *reinterpret_cast<const short8*>(&Bs[((0 * 2 + 1) * 64 + lane) * 8]), acc1, 0, 0, 0);
            acc0 = __builtin_amdgcn_mfma_f32_16x16x32_bf16(a1, *reinterpret_cast<const short8*>(&Bs[((1 * 2 + 0) * 64 + lane) * 8]), acc0, 0, 0, 0);
            acc1 = __builtin_amdgcn_mfma_f32_16x16x32_bf16(a1, *reinterpret_cast<const short8*>(&Bs[((1 * 2 + 1) * 64 + lane) * 8]), acc1, 0, 0, 0);
            #pragma unroll
            for (int ks = 2; ks < KSTEPS; ks++) {
                acc0 = __builtin_amdgcn_mfma_f32_16x16x32_bf16(af[ks - 2].s, *reinterpret_cast<const short8*>(&Bs[((ks * 2 + 0) * 64 + lane) * 8]), acc0, 0, 0, 0);
                acc1 = __builtin_amdgcn_mfma_f32_16x16x32_bf16(af[ks - 2].s, *reinterpret_cast<const short8*>(&Bs[((ks * 2 + 1) * 64 + lane) * 8]), acc1, 0, 0, 0);
            }
        } else {
            acc0 = __builtin_amdgcn_mfma_f32_16x16x32_bf16(a0, *reinterpret_cast<const short8*>(&Bs[((0 * 2 + 0) * 64 + lane) * 8]), acc0, 0, 0, 0);
            acc1 = __builtin_amdgcn_mfma_f32_16x16x32_bf16(a0, *reinterpret_cast<const short8*>(&Bs[((0 * 2 + 1) * 64 + lane) * 8]), acc1, 0, 0, 0);
            acc0 = __builtin_amdgcn_mfma_f32_16x16x32_bf16(a1, *reinterpret_cast<const short8*>(&Bs[((1 * 2 + 0) * 64 + lane) * 8]), acc0, 0, 0, 0);
            acc1 = __builtin_amdgcn_mfma_f32_16x16x32_bf16(a1, *reinterpret_cast<const short8*>(&Bs[((1 * 2 + 1) * 64 + lane) * 8]), acc1, 0, 0, 0);
        }

        // D layout: lane holds D[row=(l>>4)*4+rr][col=l&15]
        {
            int col0 = lane & 15;
            int rbase = w * 16 + (lane >> 4) * 4;
            for (int rr = 0; rr < 4; rr++) {
                gbuf[rbase + rr][col0]      = acc0[rr];
                gbuf[rbase + rr][16 + col0] = acc1[rr];
            }
        }
        __syncthreads();

        // Elementwise: this thread's 2 units.  gbuf cols are 4*ui+gate.
        {
            const float* gr = &gbuf[r][8 * p];
            float ig0 = sigmoidf_(gr[0] + bia0), fg0 = sigmoidf_(gr[1] + bif0);
            float gc0 = tanhf(gr[2] + big0),     og0 = sigmoidf_(gr[3] + bio0);
            float ig1 = sigmoidf_(gr[4] + bia1), fg1 = sigmoidf_(gr[5] + bif1);
            float gc1 = tanhf(gr[6] + big1),     og1 = sigmoidf_(gr[7] + bio1);
            c0 = fg0 * c0 + ig0 * gc0;
            c1 = fg1 * c1 + ig1 * gc1;
            float h0 = og0 * tanhf(c0);
            float h1 = og1 * tanhf(c1);

            unsigned int pk = (unsigned int)f2bf(h0) | ((unsigned int)f2bf(h1) << 16);
            __hip_atomic_store((unsigned int*)(hcur + (size_t)r * U_ + ug0), pk,
                               __ATOMIC_RELAXED, __HIP_MEMORY_SCOPE_AGENT);

            // dot partial over this block's 8 units of row r (4 lanes share r).
            float hw = h0 * wout0 + h1 * wout1;
            hw += __shfl_xor(hw, 1, 64);
            hw += __shfl_xor(hw, 2, 64);
            if (p == 0) dp[t & 31][r] = hw;
        }
        __syncthreads();   // all waves' sc1 h-stores drained (vmcnt0 before barrier)

        // Wave 0: grid barrier.  Waves 1-3: dot flush every 32 steps.
        if (tid < 64) {
            if (t < T_ - 1) {
                if (tid == 0)
                    __hip_atomic_store(&flags[b], t + 1, __ATOMIC_RELAXED, __HIP_MEMORY_SCOPE_AGENT);
                int spins = 0;
                while (__hip_atomic_load(&flags[tid], __ATOMIC_RELAXED, __HIP_MEMORY_SCOPE_AGENT) < t + 1) {
                    if (++spins > (1 << 20)) break;   // bailout: never hang
                }
            }
        } else if ((t & 31) == 31) {
            int t0 = t - 31;
            for (int idx = tid - 64; idx < 2048; idx += 192) {
                int tt = idx >> 6, rr = idx & 63;
                atomicAdd(&dot[(size_t)rr * T_ + (t0 + tt)], dp[tt][rr]);
            }
        }
        __syncthreads();
    }
}

// ---------------------------------------------------------------------------
// Kernel 4: finale.  attention collapses to scalars:
//   coef_t = (t==0) ? 1 : sum_{j<t} att_W[t,j];  shift_t = (t==0) ? 0 : att_b[t]
//   out[b,t] = sigmoid(coef_t * dot[b,t] + shift_t * sum(out_W) + out_b)
// grid = 256 (one block per t).  Output dtype follows the input dtype flag.
// ---------------------------------------------------------------------------
__global__ __launch_bounds__(256) void finale(const float* __restrict__ attWf,
                                              const float* __restrict__ attbf,
                                              const float* __restrict__ outWf,
                                              const float* __restrict__ outbf,
                                              const float* __restrict__ dot,
                                              const int* __restrict__ flag,
                                              void* __restrict__ out) {
    __shared__ float red[256];
    int t = blockIdx.x, tid = threadIdx.x;
    int fg = *flag;

    float v = (tid < t) ? attWf[(size_t)t * T_ + tid] : 0.f;
    red[tid] = v; __syncthreads();
    for (int s = 128; s > 0; s >>= 1) { if (tid < s) red[tid] += red[tid + s]; __syncthreads(); }
    float coef = (t == 0) ? 1.f : red[0];
    __syncthreads();
    red[tid] = outWf[tid] + outWf[tid + 256]; __syncthreads();
    for (int s = 128; s > 0; s >>= 1) { if (tid < s) red[tid] += red[tid + s]; __syncthreads(); }
    float sumW = red[0];

    float base = ((t == 0) ? 0.f : attbf[t]) * sumW + outbf[0];

    if (tid < B_) {
        float s = sigmoidf_(coef * dot[(size_t)tid * T_ + t] + base);
        size_t idx = (size_t)tid * T_ + t;
        if (fg) ((float*)out)[idx] = s;
        else    ((u16*)out)[idx] = f2bf(s);
    }
}

// ---------------------------------------------------------------------------
extern "C" void kernel_launch(void* const* d_in, const int* in_sizes, int n_in,
                              void* d_out, int out_size, void* d_ws, size_t ws_size,
                              hipStream_t stream) {
    const void* x    = d_in[0];   // inputs (64,256,64)
    const void* kin  = d_in[1];   // kernel (64,2048)
    const void* krec = d_in[2];   // rec_kernel (512,2048)
    const void* bias = d_in[3];   // (2048,)
    const void* attW = d_in[4];   // (256,256)
    const void* attb = d_in[5];   // (256,)
    const void* outW = d_in[6];   // (512,)
    const void* outb = d_in[7];   // ()

    if (ws_size < (size_t)WS_NEED) return;   // diagnostic: output stays memset-0

    char* ws = (char*)d_ws;
    int*   flag  = (int*)(ws + WS_FLAG);
    u16*   xb    = (u16*)(ws + WS_XB);
    u16*   Wp    = (u16*)(ws + WS_WP);
    u16*   h2    = (u16*)(ws + WS_H2);       // [2][64][512] bf16 ping-pong
    float* dot   = (float*)(ws + WS_DOT);
    float* biasf = (float*)(ws + WS_BIASF);
    float* attWf = (float*)(ws + WS_ATTWF);
    float* attbf = (float*)(ws + WS_ATTBF);
    float* outWf = (float*)(ws + WS_OUTWF);
    float* outbf = (float*)(ws + WS_OUTBF);
    int*   flags = (int*)(ws + WS_FLAGS);

    detect<<<1, 256, 0, stream>>>((const unsigned int*)kin, flag, flags);
    convert<<<4428, 256, 0, stream>>>(x, bias, attW, attb, outW, outb, flag,
                                      xb, biasf, attWf, attbf, outWf, outbf, dot);
    pack_w<<<576, 256, 0, stream>>>(kin, krec, flag, Wp);
    lstm_persist<<<64, 256, 0, stream>>>(xb, biasf, outWf, Wp, h2, dot, flags);
    finale<<<256, 256, 0, stream>>>(attWf, attbf, outWf, outbf, dot, flag, d_out);
}

// Round 6
// 1762.075 us; speedup vs baseline: 1.3887x; 1.1606x over previous
//
#include <hip/hip_runtime.h>
#include <hip/hip_bf16.h>
#include <string.h>

// Problem constants
#define B_ 64
#define T_ 256
#define F_ 64
#define U_ 512
#define G4_ 2048     // 4*U
#define KTOT 576     // F + U   (input proj folded into recurrent matmul as extra K)
#define KSTEPS 18    // KTOT/32

typedef __attribute__((ext_vector_type(8))) short short8;
typedef __attribute__((ext_vector_type(4))) float v4f;
typedef __attribute__((ext_vector_type(4))) int i4;
typedef unsigned short u16;

__device__ __forceinline__ float bf2f(u16 b) {
    unsigned int x = ((unsigned int)b) << 16;
    float f; memcpy(&f, &x, 4); return f;
}
__device__ __forceinline__ u16 f2bf(float f) {
    __hip_bfloat16 h = __float2bfloat16(f);
    u16 b; memcpy(&b, &h, 2); return b;
}
__device__ __forceinline__ float sigmoidf_(float x) { return 1.f / (1.f + __expf(-x)); }

// Dtype-flexible element load: fg=1 -> fp32, fg=0 -> bf16.
__device__ __forceinline__ float ldany(const void* p, size_t i, int fg) {
    return fg ? ((const float*)p)[i] : bf2f(((const u16*)p)[i]);
}

// Workspace layout (bytes; offsets 64-aligned).
#define WS_FLAG   0             // int dtype-flag @0
#define WS_XB     64            // bf16 [T][B][F]          2,097,152
#define WS_WP     2097216       // bf16 packed weights     2,359,296
#define WS_H2     4456512       // bf16 [2][B][U]            131,072
#define WS_DOT    4718656       // fp32 [B][T]                65,536
#define WS_BIASF  4784192       // fp32 [4U]                   8,192
#define WS_ATTWF  4792384       // fp32 [T][T]               262,144
#define WS_ATTBF  5054528       // fp32 [T]                    1,024
#define WS_OUTWF  5055552       // fp32 [U]                    2,048
#define WS_OUTBF  5057600       // fp32 [1]                       64
#define WS_FLAGS  5057664       // int [64] barrier flags        256
#define WS_NEED   5057920

// ---------------------------------------------------------------------------
// Kernel 0: dtype detection (flag: 1 = fp32 inputs, 0 = bf16) + zero the
// 64 per-block barrier flags.  Kernel-end agent release makes these visible
// to lstm_persist's sc1 polls.
// ---------------------------------------------------------------------------
__global__ __launch_bounds__(256) void detect(const unsigned int* __restrict__ w,
                                              int* __restrict__ flag,
                                              int* __restrict__ flags) {
    __shared__ int votes;
    if (threadIdx.x == 0) votes = 0;
    if (threadIdx.x < 64) flags[threadIdx.x] = 0;
    __syncthreads();
    unsigned int v = w[threadIdx.x];
    int e = (v >> 7) & 0xFF;
    if (e >= 100 && e <= 135) atomicAdd(&votes, 1);
    __syncthreads();
    if (threadIdx.x == 0) *flag = (votes < 200) ? 1 : 0;
}

// ---------------------------------------------------------------------------
// Kernel 1: canonicalize inputs.  x -> xb bf16 [T][B][F]; small arrays ->
// fp32; dot -> 0; h2 ping-pong -> 0 (so the step loop is branch-free at t=0).
// Flat task space 1,166,081; grid 4556*256.
// ---------------------------------------------------------------------------
__global__ __launch_bounds__(256) void convert(const void* __restrict__ x,
                                               const void* __restrict__ bias,
                                               const void* __restrict__ attW,
                                               const void* __restrict__ attb,
                                               const void* __restrict__ outW,
                                               const void* __restrict__ outb,
                                               const int* __restrict__ flag,
                                               u16* __restrict__ xb,
                                               float* __restrict__ biasf,
                                               float* __restrict__ attWf,
                                               float* __restrict__ attbf,
                                               float* __restrict__ outWf,
                                               float* __restrict__ outbf,
                                               float* __restrict__ dot,
                                               unsigned int* __restrict__ h2z) {
    int fg = *flag;
    size_t i = (size_t)blockIdx.x * 256 + threadIdx.x;
    if (i < 1048576) {
        float v = ldany(x, i, fg);
        int b = (int)(i >> 14), t = (int)((i >> 6) & 255), f = (int)(i & 63);
        xb[((size_t)t * B_ + b) * F_ + f] = f2bf(v);
        return;
    }
    i -= 1048576;
    if (i < 2048)  { biasf[i] = ldany(bias, i, fg); return; }
    i -= 2048;
    if (i < 65536) { attWf[i] = ldany(attW, i, fg); return; }
    i -= 65536;
    if (i < 256)   { attbf[i] = ldany(attb, i, fg); return; }
    i -= 256;
    if (i < 512)   { outWf[i] = ldany(outW, i, fg); return; }
    i -= 512;
    if (i < 1)     { outbf[i] = ldany(outb, i, fg); return; }
    i -= 1;
    if (i < 16384) { dot[i] = 0.f; return; }
    i -= 16384;
    if (i < 32768) { h2z[i] = 0u; return; }   // both h ping-pong buffers
}

// ---------------------------------------------------------------------------
// Kernel 2: pack [kernel(64,2048); rec_kernel(512,2048)] into MFMA-B-fragment
// layout, column permutation c' = 4*u + gate (orig col = gate*512 + u) so a
// 32-col slice holds all 4 gates of 8 hidden units.  Lane l of fragment
// (nt, ks) supplies B[k = ks*32 + (l>>4)*8 + j][col = nt*16 + (l&15)].
// ---------------------------------------------------------------------------
__global__ __launch_bounds__(256) void pack_w(const void* __restrict__ kin,
                                              const void* __restrict__ krec,
                                              const int* __restrict__ flag,
                                              u16* __restrict__ Wp) {
    int fg = *flag;
    int gid = blockIdx.x * 256 + threadIdx.x;   // grid = 576*256 == 128*18*64
    int lane = gid & 63;
    int frag = gid >> 6;
    int nt = frag / KSTEPS;
    int ks = frag - nt * KSTEPS;
    int kbase = ks * 32 + (lane >> 4) * 8;
    int cp = nt * 16 + (lane & 15);
    int u = cp >> 2, gate = cp & 3;
    int C = gate * U_ + u;
    short8 v;
    for (int j = 0; j < 8; j++) {
        int k = kbase + j;
        float w = (k < F_) ? ldany(kin, (size_t)k * G4_ + C, fg)
                           : ldany(krec, (size_t)(k - F_) * G4_ + C, fg);
        v[j] = (short)f2bf(w);
    }
    *reinterpret_cast<short8*>(Wp + (size_t)gid * 8) = v;
}

// ---------------------------------------------------------------------------
// Kernel 3: PERSISTENT LSTM.  64 blocks (block b owns hidden units [8b,8b+8)),
// 256 threads = 4 waves.  h + barrier flags move via sc0/sc1 coherent
// load/store (IC-coherent, bypasses the non-coherent per-XCD L2); no
// threadfence, so L2 stays warm for xb/Wp.  The 16 h-loads per lane are
// issued as ONE asm block (16 outstanding) + a single vmcnt(0) -- this is the
// fix for R5's serialized atomic-load chain (32 x 0.29us = the 7.7us step).
// c lives in 2 registers/thread.  Barrier: block publishes flags[b]=t+1 (sc1);
// wave 0's 64 lanes each poll one flag.
// ---------------------------------------------------------------------------
__global__ __launch_bounds__(256, 1) void lstm_persist(const u16* __restrict__ xb,
                                                       const float* __restrict__ biasf,
                                                       const float* __restrict__ outWf,
                                                       const u16* __restrict__ Wp,
                                                       u16* __restrict__ h2,
                                                       float* __restrict__ dot,
                                                       int* __restrict__ flags) {
    __shared__ __align__(16) u16 Bs[KSTEPS * 2 * 64 * 8];   // 36 KB weights
    __shared__ __align__(16) float gbuf[64][36];            // 9 KB gate preacts (padded)
    __shared__ float dp[32][64];                            // 8 KB dot partials

    int tid = threadIdx.x;
    int b = blockIdx.x;

    // Stage the block's B-slice (n-tiles 2b, 2b+1) into LDS: 2304 16B chunks.
    for (int i = 0; i < 9; i++) {
        int chunk = i * 256 + tid;            // 0..2303
        int ks = chunk >> 7;
        int rem = chunk & 127;
        int tile = rem >> 6;
        int lane2 = rem & 63;
        int nt = 2 * b + tile;
        short8 v = *reinterpret_cast<const short8*>(Wp + ((size_t)(nt * KSTEPS + ks) * 64 + lane2) * 8);
        *reinterpret_cast<short8*>(&Bs[((ks * 2 + tile) * 64 + lane2) * 8]) = v;
    }

    // Elementwise mapping: thread <-> (row r = tid>>2, unit pair p = tid&3);
    // owns global units ug0 = b*8+2p, ug0+1.  c in registers for all steps.
    int r  = tid >> 2;
    int p  = tid & 3;
    int ug0 = b * 8 + 2 * p;
    float bia0 = biasf[0 * U_ + ug0], bia1 = biasf[0 * U_ + ug0 + 1];
    float bif0 = biasf[1 * U_ + ug0], bif1 = biasf[1 * U_ + ug0 + 1];
    float big0 = biasf[2 * U_ + ug0], big1 = biasf[2 * U_ + ug0 + 1];
    float bio0 = biasf[3 * U_ + ug0], bio1 = biasf[3 * U_ + ug0 + 1];
    float wout0 = outWf[ug0], wout1 = outWf[ug0 + 1];
    float c0 = 0.f, c1 = 0.f;

    int w = tid >> 6, lane = tid & 63;
    int arow = w * 16 + (lane & 15);          // A-operand row (batch index)
    int koff = (lane >> 4) * 8;
    u16* hb0 = h2;                            // ping-pong buffers (both zeroed)
    u16* hb1 = h2 + B_ * U_;
    __syncthreads();

    for (int t = 0; t < T_; t++) {
        u16* hcur = (t & 1) ? hb1 : hb0;
        const u16* hprev = (t & 1) ? hb0 : hb1;
        const u16* xrow = xb + ((size_t)t * B_ + arow) * F_;

        short8 a0 = *reinterpret_cast<const short8*>(xrow + koff);        // ks=0
        short8 a1 = *reinterpret_cast<const short8*>(xrow + 32 + koff);   // ks=1

        // 16 coherent 16B h-loads, all in flight, one drain.  Base points at
        // h_prev[arow][koff]; imm offsets cover ks=2..17 (k-64 = ks*32+koff-64).
        i4 f0,f1,f2,f3,f4,f5,f6,f7,f8,f9,f10,f11,f12,f13,f14,f15;
        {
            const void* bp = (const void*)(hprev + (size_t)arow * U_ + koff);
            asm volatile(
                "global_load_dwordx4 %0,  %16, off sc0 sc1\n\t"
                "global_load_dwordx4 %1,  %16, off offset:64  sc0 sc1\n\t"
                "global_load_dwordx4 %2,  %16, off offset:128 sc0 sc1\n\t"
                "global_load_dwordx4 %3,  %16, off offset:192 sc0 sc1\n\t"
                "global_load_dwordx4 %4,  %16, off offset:256 sc0 sc1\n\t"
                "global_load_dwordx4 %5,  %16, off offset:320 sc0 sc1\n\t"
                "global_load_dwordx4 %6,  %16, off offset:384 sc0 sc1\n\t"
                "global_load_dwordx4 %7,  %16, off offset:448 sc0 sc1\n\t"
                "global_load_dwordx4 %8,  %16, off offset:512 sc0 sc1\n\t"
                "global_load_dwordx4 %9,  %16, off offset:576 sc0 sc1\n\t"
                "global_load_dwordx4 %10, %16, off offset:640 sc0 sc1\n\t"
                "global_load_dwordx4 %11, %16, off offset:704 sc0 sc1\n\t"
                "global_load_dwordx4 %12, %16, off offset:768 sc0 sc1\n\t"
                "global_load_dwordx4 %13, %16, off offset:832 sc0 sc1\n\t"
                "global_load_dwordx4 %14, %16, off offset:896 sc0 sc1\n\t"
                "global_load_dwordx4 %15, %16, off offset:960 sc0 sc1\n\t"
                "s_waitcnt vmcnt(0)"
                : "=v"(f0), "=v"(f1), "=v"(f2),  "=v"(f3),
                  "=v"(f4), "=v"(f5), "=v"(f6),  "=v"(f7),
                  "=v"(f8), "=v"(f9), "=v"(f10), "=v"(f11),
                  "=v"(f12),"=v"(f13),"=v"(f14), "=v"(f15)
                : "v"(bp)
                : "memory");
        }
        i4 hf[16] = {f0,f1,f2,f3,f4,f5,f6,f7,f8,f9,f10,f11,f12,f13,f14,f15};

        v4f acc0 = {0.f, 0.f, 0.f, 0.f}, acc1 = {0.f, 0.f, 0.f, 0.f};
        acc0 = __builtin_amdgcn_mfma_f32_16x16x32_bf16(a0, *reinterpret_cast<const short8*>(&Bs[((0 * 2 + 0) * 64 + lane) * 8]), acc0, 0, 0, 0);
        acc1 = __builtin_amdgcn_mfma_f32_16x16x32_bf16(a0, *reinterpret_cast<const short8*>(&Bs[((0 * 2 + 1) * 64 + lane) * 8]), acc1, 0, 0, 0);
        acc0 = __builtin_amdgcn_mfma_f32_16x16x32_bf16(a1, *reinterpret_cast<const short8*>(&Bs[((1 * 2 + 0) * 64 + lane) * 8]), acc0, 0, 0, 0);
        acc1 = __builtin_amdgcn_mfma_f32_16x16x32_bf16(a1, *reinterpret_cast<const short8*>(&Bs[((1 * 2 + 1) * 64 + lane) * 8]), acc1, 0, 0, 0);
        #pragma unroll
        for (int ks = 2; ks < KSTEPS; ks++) {
            short8 ah = *reinterpret_cast<const short8*>(&hf[ks - 2]);
            acc0 = __builtin_amdgcn_mfma_f32_16x16x32_bf16(ah, *reinterpret_cast<const short8*>(&Bs[((ks * 2 + 0) * 64 + lane) * 8]), acc0, 0, 0, 0);
            acc1 = __builtin_amdgcn_mfma_f32_16x16x32_bf16(ah, *reinterpret_cast<const short8*>(&Bs[((ks * 2 + 1) * 64 + lane) * 8]), acc1, 0, 0, 0);
        }

        // D layout: lane holds D[row=(l>>4)*4+rr][col=l&15]
        {
            int col0 = lane & 15;
            int rbase = w * 16 + (lane >> 4) * 4;
            for (int rr = 0; rr < 4; rr++) {
                gbuf[rbase + rr][col0]      = acc0[rr];
                gbuf[rbase + rr][16 + col0] = acc1[rr];
            }
        }
        __syncthreads();

        // Elementwise: this thread's 2 units.  gbuf cols are 4*ui+gate.
        {
            const float* gr = &gbuf[r][8 * p];
            float ig0 = sigmoidf_(gr[0] + bia0), fg0 = sigmoidf_(gr[1] + bif0);
            float gc0 = tanhf(gr[2] + big0),     og0 = sigmoidf_(gr[3] + bio0);
            float ig1 = sigmoidf_(gr[4] + bia1), fg1 = sigmoidf_(gr[5] + bif1);
            float gc1 = tanhf(gr[6] + big1),     og1 = sigmoidf_(gr[7] + bio1);
            c0 = fg0 * c0 + ig0 * gc0;
            c1 = fg1 * c1 + ig1 * gc1;
            float h0 = og0 * tanhf(c0);
            float h1 = og1 * tanhf(c1);

            unsigned int pk = (unsigned int)f2bf(h0) | ((unsigned int)f2bf(h1) << 16);
            void* sp = (void*)(hcur + (size_t)r * U_ + ug0);
            asm volatile("global_store_dword %0, %1, off sc0 sc1"
                         :: "v"(sp), "v"(pk) : "memory");

            // dot partial over this block's 8 units of row r (4 lanes share r).
            float hw = h0 * wout0 + h1 * wout1;
            hw += __shfl_xor(hw, 1, 64);
            hw += __shfl_xor(hw, 2, 64);
            if (p == 0) dp[t & 31][r] = hw;
        }
        __syncthreads();   // vmcnt(0) drain before s_barrier: h stores at IC

        // Wave 0: grid barrier.  Waves 1-3: dot flush every 32 steps.
        if (tid < 64) {
            if (t < T_ - 1) {
                if (tid == 0)
                    __hip_atomic_store(&flags[b], t + 1, __ATOMIC_RELAXED, __HIP_MEMORY_SCOPE_AGENT);
                int spins = 0;
                while (__hip_atomic_load(&flags[tid], __ATOMIC_RELAXED, __HIP_MEMORY_SCOPE_AGENT) < t + 1) {
                    if (++spins > (1 << 16)) break;   // bailout: never hang
                }
            }
        } else if ((t & 31) == 31) {
            int t0 = t - 31;
            for (int idx = tid - 64; idx < 2048; idx += 192) {
                int tt = idx >> 6, rr = idx & 63;
                atomicAdd(&dot[(size_t)rr * T_ + (t0 + tt)], dp[tt][rr]);
            }
        }
        __syncthreads();
    }
}

// ---------------------------------------------------------------------------
// Kernel 4: finale.  attention collapses to scalars:
//   coef_t = (t==0) ? 1 : sum_{j<t} att_W[t,j];  shift_t = (t==0) ? 0 : att_b[t]
//   out[b,t] = sigmoid(coef_t * dot[b,t] + shift_t * sum(out_W) + out_b)
// grid = 256 (one block per t).  Output dtype follows the input dtype flag.
// ---------------------------------------------------------------------------
__global__ __launch_bounds__(256) void finale(const float* __restrict__ attWf,
                                              const float* __restrict__ attbf,
                                              const float* __restrict__ outWf,
                                              const float* __restrict__ outbf,
                                              const float* __restrict__ dot,
                                              const int* __restrict__ flag,
                                              void* __restrict__ out) {
    __shared__ float red[256];
    int t = blockIdx.x, tid = threadIdx.x;
    int fg = *flag;

    float v = (tid < t) ? attWf[(size_t)t * T_ + tid] : 0.f;
    red[tid] = v; __syncthreads();
    for (int s = 128; s > 0; s >>= 1) { if (tid < s) red[tid] += red[tid + s]; __syncthreads(); }
    float coef = (t == 0) ? 1.f : red[0];
    __syncthreads();
    red[tid] = outWf[tid] + outWf[tid + 256]; __syncthreads();
    for (int s = 128; s > 0; s >>= 1) { if (tid < s) red[tid] += red[tid + s]; __syncthreads(); }
    float sumW = red[0];

    float base = ((t == 0) ? 0.f : attbf[t]) * sumW + outbf[0];

    if (tid < B_) {
        float s = sigmoidf_(coef * dot[(size_t)tid * T_ + t] + base);
        size_t idx = (size_t)tid * T_ + t;
        if (fg) ((float*)out)[idx] = s;
        else    ((u16*)out)[idx] = f2bf(s);
    }
}

// ---------------------------------------------------------------------------
extern "C" void kernel_launch(void* const* d_in, const int* in_sizes, int n_in,
                              void* d_out, int out_size, void* d_ws, size_t ws_size,
                              hipStream_t stream) {
    const void* x    = d_in[0];   // inputs (64,256,64)
    const void* kin  = d_in[1];   // kernel (64,2048)
    const void* krec = d_in[2];   // rec_kernel (512,2048)
    const void* bias = d_in[3];   // (2048,)
    const void* attW = d_in[4];   // (256,256)
    const void* attb = d_in[5];   // (256,)
    const void* outW = d_in[6];   // (512,)
    const void* outb = d_in[7];   // ()

    if (ws_size < (size_t)WS_NEED) return;   // diagnostic: output stays memset-0

    char* ws = (char*)d_ws;
    int*   flag  = (int*)(ws + WS_FLAG);
    u16*   xb    = (u16*)(ws + WS_XB);
    u16*   Wp    = (u16*)(ws + WS_WP);
    u16*   h2    = (u16*)(ws + WS_H2);       // [2][64][512] bf16 ping-pong
    float* dot   = (float*)(ws + WS_DOT);
    float* biasf = (float*)(ws + WS_BIASF);
    float* attWf = (float*)(ws + WS_ATTWF);
    float* attbf = (float*)(ws + WS_ATTBF);
    float* outWf = (float*)(ws + WS_OUTWF);
    float* outbf = (float*)(ws + WS_OUTBF);
    int*   flags = (int*)(ws + WS_FLAGS);

    detect<<<1, 256, 0, stream>>>((const unsigned int*)kin, flag, flags);
    convert<<<4556, 256, 0, stream>>>(x, bias, attW, attb, outW, outb, flag,
                                      xb, biasf, attWf, attbf, outWf, outbf, dot,
                                      (unsigned int*)h2);
    pack_w<<<576, 256, 0, stream>>>(kin, krec, flag, Wp);
    lstm_persist<<<64, 256, 0, stream>>>(xb, biasf, outWf, Wp, h2, dot, flags);
    finale<<<256, 256, 0, stream>>>(attWf, attbf, outWf, outbf, dot, flag, d_out);
}

// Round 7
// 1312.808 us; speedup vs baseline: 1.8639x; 1.3422x over previous
//
#include <hip/hip_runtime.h>
#include <hip/hip_bf16.h>
#include <string.h>

// Problem constants
#define B_ 64
#define T_ 256
#define F_ 64
#define U_ 512
#define G4_ 2048     // 4*U
#define KTOT 576     // F + U   (input proj folded into recurrent matmul as extra K)
#define KSTEPS 18    // KTOT/32

typedef __attribute__((ext_vector_type(8))) short short8;
typedef __attribute__((ext_vector_type(4))) float v4f;
typedef __attribute__((ext_vector_type(4))) int i4;
typedef unsigned short u16;

__device__ __forceinline__ float bf2f(u16 b) {
    unsigned int x = ((unsigned int)b) << 16;
    float f; memcpy(&f, &x, 4); return f;
}
__device__ __forceinline__ u16 f2bf(float f) {
    __hip_bfloat16 h = __float2bfloat16(f);
    u16 b; memcpy(&b, &h, 2); return b;
}
__device__ __forceinline__ float sigmoidf_(float x) { return 1.f / (1.f + __expf(-x)); }

// Dtype-flexible element load: fg=1 -> fp32, fg=0 -> bf16.
__device__ __forceinline__ float ldany(const void* p, size_t i, int fg) {
    return fg ? ((const float*)p)[i] : bf2f(((const u16*)p)[i]);
}

// Workspace layout (bytes; offsets 64-aligned).
#define WS_FLAG   0             // int dtype-flag @0
#define WS_XB     64            // bf16 [T][B][F]          2,097,152
#define WS_WP     2097216       // bf16 packed weights     2,359,296
#define WS_H2     4456512       // bf16 [2][B][U]            131,072
#define WS_DOT    4718656       // fp32 [B][T]                65,536
#define WS_BIASF  4784192       // fp32 [4U]                   8,192
#define WS_ATTWF  4792384       // fp32 [T][T]               262,144
#define WS_ATTBF  5054528       // fp32 [T]                    1,024
#define WS_OUTWF  5055552       // fp32 [U]                    2,048
#define WS_OUTBF  5057600       // fp32 [1]                       64
#define WS_NEED   5057920

// ---------------------------------------------------------------------------
// Kernel 0: dtype detection (flag: 1 = fp32 inputs, 0 = bf16).
// ---------------------------------------------------------------------------
__global__ __launch_bounds__(256) void detect(const unsigned int* __restrict__ w,
                                              int* __restrict__ flag) {
    __shared__ int votes;
    if (threadIdx.x == 0) votes = 0;
    __syncthreads();
    unsigned int v = w[threadIdx.x];
    int e = (v >> 7) & 0xFF;
    if (e >= 100 && e <= 135) atomicAdd(&votes, 1);
    __syncthreads();
    if (threadIdx.x == 0) *flag = (votes < 200) ? 1 : 0;
}

// ---------------------------------------------------------------------------
// Kernel 1: canonicalize inputs.  x -> xb bf16 [T][B][F]; small arrays ->
// fp32; dot -> 0; h2 ping-pong -> 0.  NOTE: zeroed h has LSB tag 0 == stale
// for every read step's expected tag (see lstm_persist tag schedule), except
// t=0 where the check is skipped and zeros are the correct h_{-1}.
// ---------------------------------------------------------------------------
__global__ __launch_bounds__(256) void convert(const void* __restrict__ x,
                                               const void* __restrict__ bias,
                                               const void* __restrict__ attW,
                                               const void* __restrict__ attb,
                                               const void* __restrict__ outW,
                                               const void* __restrict__ outb,
                                               const int* __restrict__ flag,
                                               u16* __restrict__ xb,
                                               float* __restrict__ biasf,
                                               float* __restrict__ attWf,
                                               float* __restrict__ attbf,
                                               float* __restrict__ outWf,
                                               float* __restrict__ outbf,
                                               float* __restrict__ dot,
                                               unsigned int* __restrict__ h2z) {
    int fg = *flag;
    size_t i = (size_t)blockIdx.x * 256 + threadIdx.x;
    if (i < 1048576) {
        float v = ldany(x, i, fg);
        int b = (int)(i >> 14), t = (int)((i >> 6) & 255), f = (int)(i & 63);
        xb[((size_t)t * B_ + b) * F_ + f] = f2bf(v);
        return;
    }
    i -= 1048576;
    if (i < 2048)  { biasf[i] = ldany(bias, i, fg); return; }
    i -= 2048;
    if (i < 65536) { attWf[i] = ldany(attW, i, fg); return; }
    i -= 65536;
    if (i < 256)   { attbf[i] = ldany(attb, i, fg); return; }
    i -= 256;
    if (i < 512)   { outWf[i] = ldany(outW, i, fg); return; }
    i -= 512;
    if (i < 1)     { outbf[i] = ldany(outb, i, fg); return; }
    i -= 1;
    if (i < 16384) { dot[i] = 0.f; return; }
    i -= 16384;
    if (i < 32768) { h2z[i] = 0u; return; }   // both h ping-pong buffers
}

// ---------------------------------------------------------------------------
// Kernel 2: pack [kernel(64,2048); rec_kernel(512,2048)] into MFMA-B-fragment
// layout, column permutation c' = 4*u + gate so a 32-col slice holds all 4
// gates of 8 hidden units.  Lane l of fragment (nt, ks) supplies
// B[k = ks*32 + (l>>4)*8 + j][col = nt*16 + (l&15)].
// ---------------------------------------------------------------------------
__global__ __launch_bounds__(256) void pack_w(const void* __restrict__ kin,
                                              const void* __restrict__ krec,
                                              const int* __restrict__ flag,
                                              u16* __restrict__ Wp) {
    int fg = *flag;
    int gid = blockIdx.x * 256 + threadIdx.x;   // grid = 576*256 == 128*18*64
    int lane = gid & 63;
    int frag = gid >> 6;
    int nt = frag / KSTEPS;
    int ks = frag - nt * KSTEPS;
    int kbase = ks * 32 + (lane >> 4) * 8;
    int cp = nt * 16 + (lane & 15);
    int u = cp >> 2, gate = cp & 3;
    int C = gate * U_ + u;
    short8 v;
    for (int j = 0; j < 8; j++) {
        int k = kbase + j;
        float w = (k < F_) ? ldany(kin, (size_t)k * G4_ + C, fg)
                           : ldany(krec, (size_t)(k - F_) * G4_ + C, fg);
        v[j] = (short)f2bf(w);
    }
    *reinterpret_cast<short8*>(Wp + (size_t)gid * 8) = v;
}

// ---------------------------------------------------------------------------
// Kernel 3: PERSISTENT LSTM, BARRIER-FREE.  64 blocks (block b owns hidden
// units [8b,8b+8)), 256 threads = 4 waves.  Freshness of h is IN-BAND: every
// stored bf16 h has its LSB forced to tag(t) = ((t>>1)&1)^1, which alternates
// on each reuse of a ping-pong buffer (and differs from the zero-init's 0).
// Consumers poll the h region itself (16 coherent 16B loads, one vmcnt) and
// accept when ALL 64 dwords carry the expected tag; each dword is a single
// producer-thread store, so per-dword checking is store-granular.  This cuts
// the R6 critical path (drain + flag-publish + flag-poll + h-load ~ 4 IC
// trips) to store-propagate + poll-load ~ 2 trips, and removes all barriers.
// 2-buffer safety without barriers: overwriting buf[t&1] with h_{t+2}
// requires having consumed all of h_{t+1}, which certifies every block
// stored h_{t+1}, which certifies every block finished reading buf[t&1].
// c lives in 2 registers/thread.
// ---------------------------------------------------------------------------
__global__ __launch_bounds__(256, 1) void lstm_persist(const u16* __restrict__ xb,
                                                       const float* __restrict__ biasf,
                                                       const float* __restrict__ outWf,
                                                       const u16* __restrict__ Wp,
                                                       u16* __restrict__ h2,
                                                       float* __restrict__ dot) {
    __shared__ __align__(16) u16 Bs[KSTEPS * 2 * 64 * 8];   // 36 KB weights
    __shared__ __align__(16) float gbuf[64][36];            // 9 KB gate preacts (padded)
    __shared__ float dp[32][64];                            // 8 KB dot partials

    int tid = threadIdx.x;
    int b = blockIdx.x;

    // Stage the block's B-slice (n-tiles 2b, 2b+1) into LDS: 2304 16B chunks.
    for (int i = 0; i < 9; i++) {
        int chunk = i * 256 + tid;            // 0..2303
        int ks = chunk >> 7;
        int rem = chunk & 127;
        int tile = rem >> 6;
        int lane2 = rem & 63;
        int nt = 2 * b + tile;
        short8 v = *reinterpret_cast<const short8*>(Wp + ((size_t)(nt * KSTEPS + ks) * 64 + lane2) * 8);
        *reinterpret_cast<short8*>(&Bs[((ks * 2 + tile) * 64 + lane2) * 8]) = v;
    }

    // Elementwise mapping: thread <-> (row r = tid>>2, unit pair p = tid&3);
    // owns global units ug0 = b*8+2p, ug0+1.  c in registers for all steps.
    int r  = tid >> 2;
    int p  = tid & 3;
    int ug0 = b * 8 + 2 * p;
    float bia0 = biasf[0 * U_ + ug0], bia1 = biasf[0 * U_ + ug0 + 1];
    float bif0 = biasf[1 * U_ + ug0], bif1 = biasf[1 * U_ + ug0 + 1];
    float big0 = biasf[2 * U_ + ug0], big1 = biasf[2 * U_ + ug0 + 1];
    float bio0 = biasf[3 * U_ + ug0], bio1 = biasf[3 * U_ + ug0 + 1];
    float wout0 = outWf[ug0], wout1 = outWf[ug0 + 1];
    float c0 = 0.f, c1 = 0.f;

    int w = tid >> 6, lane = tid & 63;
    int arow = w * 16 + (lane & 15);          // A-operand row (batch index)
    int koff = (lane >> 4) * 8;
    u16* hb0 = h2;                            // ping-pong buffers (both zeroed)
    u16* hb1 = h2 + B_ * U_;
    __syncthreads();

    for (int t = 0; t < T_; t++) {
        u16* hcur = (t & 1) ? hb1 : hb0;
        const u16* hprev = (t & 1) ? hb0 : hb1;
        const u16* xrow = xb + ((size_t)t * B_ + arow) * F_;
        unsigned int wtag = ((unsigned)(t >> 1) & 1u) ^ 1u;                 // write tag
        unsigned int rpat = ((((unsigned)(t - 1) >> 1) & 1u) ^ 1u) * 0x00010001u; // read pattern

        short8 a0 = *reinterpret_cast<const short8*>(xrow + koff);        // ks=0
        short8 a1 = *reinterpret_cast<const short8*>(xrow + 32 + koff);   // ks=1

        // x-part MFMAs issue before the h poll (hidden under IC latency).
        v4f acc0 = {0.f, 0.f, 0.f, 0.f}, acc1 = {0.f, 0.f, 0.f, 0.f};
        acc0 = __builtin_amdgcn_mfma_f32_16x16x32_bf16(a0, *reinterpret_cast<const short8*>(&Bs[((0 * 2 + 0) * 64 + lane) * 8]), acc0, 0, 0, 0);
        acc1 = __builtin_amdgcn_mfma_f32_16x16x32_bf16(a0, *reinterpret_cast<const short8*>(&Bs[((0 * 2 + 1) * 64 + lane) * 8]), acc1, 0, 0, 0);
        acc0 = __builtin_amdgcn_mfma_f32_16x16x32_bf16(a1, *reinterpret_cast<const short8*>(&Bs[((1 * 2 + 0) * 64 + lane) * 8]), acc0, 0, 0, 0);
        acc1 = __builtin_amdgcn_mfma_f32_16x16x32_bf16(a1, *reinterpret_cast<const short8*>(&Bs[((1 * 2 + 1) * 64 + lane) * 8]), acc1, 0, 0, 0);

        // Poll-load h_{t-1}: 16 coherent 16B loads, all in flight, one drain;
        // accept when every dword carries the expected tag (wave-unanimous).
        i4 f0,f1,f2,f3,f4,f5,f6,f7,f8,f9,f10,f11,f12,f13,f14,f15;
        {
            const void* bp = (const void*)(hprev + (size_t)arow * U_ + koff);
            int spins = 0;
            for (;;) {
                asm volatile(
                    "global_load_dwordx4 %0,  %16, off sc0 sc1\n\t"
                    "global_load_dwordx4 %1,  %16, off offset:64  sc0 sc1\n\t"
                    "global_load_dwordx4 %2,  %16, off offset:128 sc0 sc1\n\t"
                    "global_load_dwordx4 %3,  %16, off offset:192 sc0 sc1\n\t"
                    "global_load_dwordx4 %4,  %16, off offset:256 sc0 sc1\n\t"
                    "global_load_dwordx4 %5,  %16, off offset:320 sc0 sc1\n\t"
                    "global_load_dwordx4 %6,  %16, off offset:384 sc0 sc1\n\t"
                    "global_load_dwordx4 %7,  %16, off offset:448 sc0 sc1\n\t"
                    "global_load_dwordx4 %8,  %16, off offset:512 sc0 sc1\n\t"
                    "global_load_dwordx4 %9,  %16, off offset:576 sc0 sc1\n\t"
                    "global_load_dwordx4 %10, %16, off offset:640 sc0 sc1\n\t"
                    "global_load_dwordx4 %11, %16, off offset:704 sc0 sc1\n\t"
                    "global_load_dwordx4 %12, %16, off offset:768 sc0 sc1\n\t"
                    "global_load_dwordx4 %13, %16, off offset:832 sc0 sc1\n\t"
                    "global_load_dwordx4 %14, %16, off offset:896 sc0 sc1\n\t"
                    "global_load_dwordx4 %15, %16, off offset:960 sc0 sc1\n\t"
                    "s_waitcnt vmcnt(0)"
                    : "=v"(f0), "=v"(f1), "=v"(f2),  "=v"(f3),
                      "=v"(f4), "=v"(f5), "=v"(f6),  "=v"(f7),
                      "=v"(f8), "=v"(f9), "=v"(f10), "=v"(f11),
                      "=v"(f12),"=v"(f13),"=v"(f14), "=v"(f15)
                    : "v"(bp)
                    : "memory");
                if (t == 0) break;            // zeros are the correct h_{-1}
                unsigned bad = 0;
                #define CK(f) bad |= (((unsigned)(f)[0]) ^ rpat) & 0x00010001u; \
                              bad |= (((unsigned)(f)[1]) ^ rpat) & 0x00010001u; \
                              bad |= (((unsigned)(f)[2]) ^ rpat) & 0x00010001u; \
                              bad |= (((unsigned)(f)[3]) ^ rpat) & 0x00010001u;
                CK(f0) CK(f1) CK(f2)  CK(f3)  CK(f4)  CK(f5)  CK(f6)  CK(f7)
                CK(f8) CK(f9) CK(f10) CK(f11) CK(f12) CK(f13) CK(f14) CK(f15)
                #undef CK
                if (__ballot(bad == 0) == ~0ull) break;
                if (++spins > (1 << 15)) break;   // bailout: never hang
            }
        }
        i4 hf[16] = {f0,f1,f2,f3,f4,f5,f6,f7,f8,f9,f10,f11,f12,f13,f14,f15};

        #pragma unroll
        for (int ks = 2; ks < KSTEPS; ks++) {
            short8 ah = *reinterpret_cast<const short8*>(&hf[ks - 2]);
            acc0 = __builtin_amdgcn_mfma_f32_16x16x32_bf16(ah, *reinterpret_cast<const short8*>(&Bs[((ks * 2 + 0) * 64 + lane) * 8]), acc0, 0, 0, 0);
            acc1 = __builtin_amdgcn_mfma_f32_16x16x32_bf16(ah, *reinterpret_cast<const short8*>(&Bs[((ks * 2 + 1) * 64 + lane) * 8]), acc1, 0, 0, 0);
        }

        // D layout: lane holds D[row=(l>>4)*4+rr][col=l&15]
        {
            int col0 = lane & 15;
            int rbase = w * 16 + (lane >> 4) * 4;
            for (int rr = 0; rr < 4; rr++) {
                gbuf[rbase + rr][col0]      = acc0[rr];
                gbuf[rbase + rr][16 + col0] = acc1[rr];
            }
        }
        __syncthreads();

        // Elementwise: this thread's 2 units.  gbuf cols are 4*ui+gate.
        {
            const float* gr = &gbuf[r][8 * p];
            float ig0 = sigmoidf_(gr[0] + bia0), fg0 = sigmoidf_(gr[1] + bif0);
            float gc0 = tanhf(gr[2] + big0),     og0 = sigmoidf_(gr[3] + bio0);
            float ig1 = sigmoidf_(gr[4] + bia1), fg1 = sigmoidf_(gr[5] + bif1);
            float gc1 = tanhf(gr[6] + big1),     og1 = sigmoidf_(gr[7] + bio1);
            c0 = fg0 * c0 + ig0 * gc0;
            c1 = fg1 * c1 + ig1 * gc1;
            float h0 = og0 * tanhf(c0);
            float h1 = og1 * tanhf(c1);

            // Pack with in-band freshness tag in each bf16's LSB.
            unsigned int pk = (unsigned int)(((unsigned)f2bf(h0) & 0xFFFEu) | wtag)
                            | ((unsigned int)(((unsigned)f2bf(h1) & 0xFFFEu) | wtag) << 16);
            void* sp = (void*)(hcur + (size_t)r * U_ + ug0);
            asm volatile("global_store_dword %0, %1, off sc0 sc1"
                         :: "v"(sp), "v"(pk) : "memory");

            // dot partial over this block's 8 units of row r (untagged h).
            float hw = h0 * wout0 + h1 * wout1;
            hw += __shfl_xor(hw, 1, 64);
            hw += __shfl_xor(hw, 2, 64);
            if (p == 0) dp[t & 31][r] = hw;
        }
        __syncthreads();

        // Flush dot partials every 32 steps (2048 entries, 8 atomics/thread).
        if ((t & 31) == 31) {
            int t0 = t - 31;
            for (int idx = tid; idx < 2048; idx += 256) {
                int tt = idx >> 6, rr = idx & 63;
                atomicAdd(&dot[(size_t)rr * T_ + (t0 + tt)], dp[tt][rr]);
            }
        }
    }
}

// ---------------------------------------------------------------------------
// Kernel 4: finale.  attention collapses to scalars:
//   coef_t = (t==0) ? 1 : sum_{j<t} att_W[t,j];  shift_t = (t==0) ? 0 : att_b[t]
//   out[b,t] = sigmoid(coef_t * dot[b,t] + shift_t * sum(out_W) + out_b)
// grid = 256 (one block per t).  Output dtype follows the input dtype flag.
// ---------------------------------------------------------------------------
__global__ __launch_bounds__(256) void finale(const float* __restrict__ attWf,
                                              const float* __restrict__ attbf,
                                              const float* __restrict__ outWf,
                                              const float* __restrict__ outbf,
                                              const float* __restrict__ dot,
                                              const int* __restrict__ flag,
                                              void* __restrict__ out) {
    __shared__ float red[256];
    int t = blockIdx.x, tid = threadIdx.x;
    int fg = *flag;

    float v = (tid < t) ? attWf[(size_t)t * T_ + tid] : 0.f;
    red[tid] = v; __syncthreads();
    for (int s = 128; s > 0; s >>= 1) { if (tid < s) red[tid] += red[tid + s]; __syncthreads(); }
    float coef = (t == 0) ? 1.f : red[0];
    __syncthreads();
    red[tid] = outWf[tid] + outWf[tid + 256]; __syncthreads();
    for (int s = 128; s > 0; s >>= 1) { if (tid < s) red[tid] += red[tid + s]; __syncthreads(); }
    float sumW = red[0];

    float base = ((t == 0) ? 0.f : attbf[t]) * sumW + outbf[0];

    if (tid < B_) {
        float s = sigmoidf_(coef * dot[(size_t)tid * T_ + t] + base);
        size_t idx = (size_t)tid * T_ + t;
        if (fg) ((float*)out)[idx] = s;
        else    ((u16*)out)[idx] = f2bf(s);
    }
}

// ---------------------------------------------------------------------------
extern "C" void kernel_launch(void* const* d_in, const int* in_sizes, int n_in,
                              void* d_out, int out_size, void* d_ws, size_t ws_size,
                              hipStream_t stream) {
    const void* x    = d_in[0];   // inputs (64,256,64)
    const void* kin  = d_in[1];   // kernel (64,2048)
    const void* krec = d_in[2];   // rec_kernel (512,2048)
    const void* bias = d_in[3];   // (2048,)
    const void* attW = d_in[4];   // (256,256)
    const void* attb = d_in[5];   // (256,)
    const void* outW = d_in[6];   // (512,)
    const void* outb = d_in[7];   // ()

    if (ws_size < (size_t)WS_NEED) return;   // diagnostic: output stays memset-0

    char* ws = (char*)d_ws;
    int*   flag  = (int*)(ws + WS_FLAG);
    u16*   xb    = (u16*)(ws + WS_XB);
    u16*   Wp    = (u16*)(ws + WS_WP);
    u16*   h2    = (u16*)(ws + WS_H2);       // [2][64][512] bf16 ping-pong
    float* dot   = (float*)(ws + WS_DOT);
    float* biasf = (float*)(ws + WS_BIASF);
    float* attWf = (float*)(ws + WS_ATTWF);
    float* attbf = (float*)(ws + WS_ATTBF);
    float* outWf = (float*)(ws + WS_OUTWF);
    float* outbf = (float*)(ws + WS_OUTBF);

    detect<<<1, 256, 0, stream>>>((const unsigned int*)kin, flag);
    convert<<<4556, 256, 0, stream>>>(x, bias, attW, attb, outW, outb, flag,
                                      xb, biasf, attWf, attbf, outWf, outbf, dot,
                                      (unsigned int*)h2);
    pack_w<<<576, 256, 0, stream>>>(kin, krec, flag, Wp);
    lstm_persist<<<64, 256, 0, stream>>>(xb, biasf, outWf, Wp, h2, dot);
    finale<<<256, 256, 0, stream>>>(attWf, attbf, outWf, outbf, dot, flag, d_out);
}